// Round 14
// baseline (524.314 us; speedup 1.0000x reference)
//
#include <hip/hip_runtime.h>
#include <hip/hip_bf16.h>
#include <math.h>

#define HC 256
#define NH 8
#define NEG_SLOPE 0.2f
#define CHW 64   // edges per chunk per wave (aggregation)
#define LDA 136  // LDS row stride in u16 (272 B): 2-way read pattern (free)

typedef unsigned short u16;
typedef __attribute__((ext_vector_type(8))) short bf16x8;
typedef __attribute__((ext_vector_type(4))) float f32x4;

__device__ __forceinline__ u16 f2bf(float f) {
    unsigned int u = __float_as_uint(f);
    u += 0x7FFFu + ((u >> 16) & 1u);
    return (u16)(u >> 16);
}
__device__ __forceinline__ float bf2f(u16 s) {
    return __uint_as_float(((unsigned int)s) << 16);
}
__device__ __forceinline__ f32x4 bf4f(ushort4 v) {
    f32x4 r;
    r[0] = bf2f(v.x); r[1] = bf2f(v.y); r[2] = bf2f(v.z); r[3] = bf2f(v.w);
    return r;
}

// raw barrier: own LDS writes drained -> all-wave barrier -> no read hoisting.
// Global loads in flight are NOT drained (unlike __syncthreads' vmcnt(0)).
#define BAR_LDS()                                                  \
    do {                                                           \
        asm volatile("s_waitcnt lgkmcnt(0)" ::: "memory");         \
        __builtin_amdgcn_s_barrier();                              \
        __builtin_amdgcn_sched_barrier(0);                         \
    } while (0)

// ---------------------------------------------------------------------------
// pack B (fp32 [K x 256]) -> hi/lo, fragment-major:
// chunk g = kt*1024 + f*64 + lane; col = f*16 + (lane&15); k = kt*32+(lane>>4)*8+e
// ---------------------------------------------------------------------------
__global__ __launch_bounds__(256) void pack_b_split(const float* __restrict__ B, int K,
                                                    u16* __restrict__ Bh,
                                                    u16* __restrict__ Bl) {
    const int g = blockIdx.x * 256 + threadIdx.x;
    const int lane = g & 63;
    const int f = (g >> 6) & 15;
    const int kt = g >> 10;
    const int col = f * 16 + (lane & 15);
    const int k0 = kt * 32 + (lane >> 4) * 8;
    bf16x8 hv, lv;
#pragma unroll
    for (int e = 0; e < 8; e++) {
        const float v = B[(size_t)(k0 + e) * HC + col];
        const u16 h = f2bf(v);
        hv[e] = (short)h;
        lv[e] = (short)f2bf(v - bf2f(h));
    }
    const size_t off = (size_t)g * 8;
    *(bf16x8*)(Bh + off) = hv;
    *(bf16x8*)(Bl + off) = lv;
}

// ---------------------------------------------------------------------------
// Fused MFMA GEMM: C = Ah*(Bh + Bl), A bf16-rounded once, B split.
// 256 threads / 4 waves. Tile M=64, N=256; wave w owns cols [w*64, w*64+64).
// A is fetched in 128-B-contiguous-per-thread bursts, 4 k-tiles per group
// (DRAM page locality), converted once, staged to [64][LDA] bf16 LDS.
// Double-buffered groups, ONE barrier per 4 k-tiles; B reg-dbuf (static sets).
// Requires K % 128 == 0 (K = 1280 or 256).
// ---------------------------------------------------------------------------
__global__ __launch_bounds__(256) void gemm_fused_split(
    const float* __restrict__ A,
    const u16* __restrict__ Bh, const u16* __restrict__ Bl,
    float* __restrict__ C, int M, int K) {
    __shared__ u16 ldsA[2][64 * LDA];   // 2 x 17.4 KB
    const int tid = threadIdx.x;
    const int wid = tid >> 6;        // 0..3
    const int lane = tid & 63;
    const int rowblk = blockIdx.x;
    const int KT = K >> 5;           // 32-k tiles (40 or 8)
    const int NG4 = K >> 7;          // 128-k groups (10 or 2)

    f32x4 acc[4][4];
#pragma unroll
    for (int i = 0; i < 4; i++)
#pragma unroll
        for (int j = 0; j < 4; j++) acc[i][j] = (f32x4)0.f;

    // staging map: thread t -> row t>>2, 32 consecutive floats at (t&3)*32
    const int srow = tid >> 2;
    const int scc = (tid & 3) * 32;
    const int grow = rowblk * 64 + srow;
    const float* aptr = (grow < M) ? (A + (size_t)grow * K + scc) : nullptr;
    const int woff = srow * LDA + scc;   // u16 units; 16-B aligned

    float4 pf[8];
    auto loadAg = [&](int g) {
#pragma unroll
        for (int q = 0; q < 8; q++) {
            pf[q] = make_float4(0.f, 0.f, 0.f, 0.f);
            if (aptr) pf[q] = *(const float4*)(aptr + g * 128 + q * 4);
        }
    };
    auto stageg = [&](int buf) {
#pragma unroll
        for (int p = 0; p < 4; p++) {
            const float vv[8] = {pf[2 * p].x,     pf[2 * p].y,
                                 pf[2 * p].z,     pf[2 * p].w,
                                 pf[2 * p + 1].x, pf[2 * p + 1].y,
                                 pf[2 * p + 1].z, pf[2 * p + 1].w};
            bf16x8 hv;
#pragma unroll
            for (int e = 0; e < 8; e++) hv[e] = (short)f2bf(vv[e]);
            *(bf16x8*)&ldsA[buf][woff + p * 8] = hv;
        }
    };
    auto readA = [&](int buf, int kk, bf16x8* ah) {
#pragma unroll
        for (int i = 0; i < 4; i++)
            ah[i] = *(const bf16x8*)&ldsA[buf][(i * 16 + (lane & 15)) * LDA +
                                              kk * 32 + (lane >> 4) * 8];
    };
    auto loadB = [&](int kt, bf16x8* bh, bf16x8* bl) {
        const u16* bHp = Bh + ((size_t)kt * 16 + wid * 4) * 512 + lane * 8;
        const u16* bLp = Bl + ((size_t)kt * 16 + wid * 4) * 512 + lane * 8;
#pragma unroll
        for (int j = 0; j < 4; j++) {
            bh[j] = *(const bf16x8*)(bHp + j * 512);
            bl[j] = *(const bf16x8*)(bLp + j * 512);
        }
    };
    auto mfma_tile = [&](const bf16x8* ah, const bf16x8* bh, const bf16x8* bl) {
#pragma unroll
        for (int i = 0; i < 4; i++)
#pragma unroll
            for (int j = 0; j < 4; j++) {
                acc[i][j] = __builtin_amdgcn_mfma_f32_16x16x32_bf16(ah[i], bh[j], acc[i][j], 0, 0, 0);
                acc[i][j] = __builtin_amdgcn_mfma_f32_16x16x32_bf16(ah[i], bl[j], acc[i][j], 0, 0, 0);
            }
    };

    // preamble: group 0 staged in buf 0; group 1 loads in flight in pf
    loadAg(0);
    stageg(0);
    if (NG4 > 1) loadAg(1);
    bf16x8 b0h[4], b0l[4], b1h[4], b1l[4];
    loadB(0, b0h, b0l);
    BAR_LDS();

    int cur = 0;
    for (int g = 0; g < NG4; ++g) {
        // stage group g+1 (pf) into the other buffer, then issue loads for g+2.
        // Safe: all waves finished reading buf cur^1 before the last barrier.
        if (g + 1 < NG4) stageg(cur ^ 1);
        if (g + 2 < NG4) loadAg(g + 2);

        const int kt0 = g * 4;
        {   // kk = 0 (B set 0); prefetch kt0+1 -> set 1
            loadB(kt0 + 1 < KT ? kt0 + 1 : kt0, b1h, b1l);
            bf16x8 ah[4];
            readA(cur, 0, ah);
            mfma_tile(ah, b0h, b0l);
        }
        {   // kk = 1 (B set 1); prefetch kt0+2 -> set 0
            loadB(kt0 + 2 < KT ? kt0 + 2 : kt0, b0h, b0l);
            bf16x8 ah[4];
            readA(cur, 1, ah);
            mfma_tile(ah, b1h, b1l);
        }
        {   // kk = 2 (B set 0); prefetch kt0+3 -> set 1
            loadB(kt0 + 3 < KT ? kt0 + 3 : kt0, b1h, b1l);
            bf16x8 ah[4];
            readA(cur, 2, ah);
            mfma_tile(ah, b0h, b0l);
        }
        {   // kk = 3 (B set 1); prefetch kt0+4 -> set 0 (next group's first)
            loadB(kt0 + 4 < KT ? kt0 + 4 : kt0, b0h, b0l);   // FIXED ternary
            bf16x8 ah[4];
            readA(cur, 3, ah);
            mfma_tile(ah, b1h, b1l);
        }
        BAR_LDS();
        cur ^= 1;
    }

    // epilogue: C/D layout col = lane&15, row = (lane>>4)*4 + r
    const int r0 = rowblk * 64;
    const int colb = wid * 64 + (lane & 15);
#pragma unroll
    for (int i = 0; i < 4; i++) {
#pragma unroll
        for (int r = 0; r < 4; r++) {
            const int row = r0 + i * 16 + (lane >> 4) * 4 + r;
            if (row < M) {
#pragma unroll
                for (int j = 0; j < 4; j++)
                    C[(size_t)row * HC + colb + j * 16] = acc[i][j][r];
            }
        }
    }
}

// ---------------------------------------------------------------------------
// Per-node attention coefficients + bf16 copy of h for the gather
// ---------------------------------------------------------------------------
__global__ __launch_bounds__(256) void attn_coef(const float* __restrict__ h,
                                                 const float* __restrict__ att_s,
                                                 const float* __restrict__ att_d,
                                                 float* __restrict__ a_src,
                                                 float* __restrict__ a_dst,
                                                 u16* __restrict__ h_bf) {
    const int n = blockIdx.x;
    const int tid = threadIdx.x;
    const float hv = h[(size_t)n * HC + tid];
    h_bf[(size_t)n * HC + tid] = f2bf(hv);
    float p = hv * att_s[tid];
    float q = hv * att_d[tid];
#pragma unroll
    for (int m = 16; m >= 1; m >>= 1) {
        p += __shfl_xor(p, m);
        q += __shfl_xor(q, m);
    }
    if ((tid & 31) == 0) {
        a_src[n * NH + (tid >> 5)] = p;
        a_dst[n * NH + (tid >> 5)] = q;
    }
}

// ---------------------------------------------------------------------------
// CSR build: count, two-level scan, scatter (stores resolved src ids)
// ---------------------------------------------------------------------------
__global__ void count_deg(const int* __restrict__ dst, int E, int ET, int* __restrict__ deg) {
    const int e = blockIdx.x * blockDim.x + threadIdx.x;
    if (e >= ET) return;
    const int d = (e < E) ? dst[e] : (e - E);
    atomicAdd(&deg[d], 1);
}

__global__ __launch_bounds__(256) void scan_block(const int* __restrict__ deg,
                                                  int* __restrict__ row_ptr,
                                                  int* __restrict__ partials, int N) {
    __shared__ int sd[256];
    const int tid = threadIdx.x;
    const int base = blockIdx.x * 1024 + tid * 4;
    int v0 = (base + 0 < N) ? deg[base + 0] : 0;
    int v1 = (base + 1 < N) ? deg[base + 1] : 0;
    int v2 = (base + 2 < N) ? deg[base + 2] : 0;
    int v3 = (base + 3 < N) ? deg[base + 3] : 0;
    const int tsum = v0 + v1 + v2 + v3;
    sd[tid] = tsum;
    __syncthreads();
    int run = tsum;
    for (int off = 1; off < 256; off <<= 1) {
        int t = 0;
        if (tid >= off) t = sd[tid - off];
        __syncthreads();
        run += t;
        sd[tid] = run;
        __syncthreads();
    }
    const int excl = run - tsum;
    int s0 = excl + v0, s1 = s0 + v1, s2 = s1 + v2, s3 = s2 + v3;
    if (base + 0 < N) row_ptr[base + 1] = s0;
    if (base + 1 < N) row_ptr[base + 2] = s1;
    if (base + 2 < N) row_ptr[base + 3] = s2;
    if (base + 3 < N) row_ptr[base + 4] = s3;
    if (tid == 255) partials[blockIdx.x] = run;
}

__global__ __launch_bounds__(1024) void scan_partials(int* __restrict__ partials, int nb) {
    __shared__ int sd[1024];
    const int tid = threadIdx.x;
    int v = (tid < nb) ? partials[tid] : 0;
    sd[tid] = v;
    __syncthreads();
    int run = v;
    for (int off = 1; off < 1024; off <<= 1) {
        int t = 0;
        if (tid >= off) t = sd[tid - off];
        __syncthreads();
        run += t;
        sd[tid] = run;
        __syncthreads();
    }
    if (tid < nb) partials[tid] = run - v;  // exclusive
}

__global__ __launch_bounds__(256) void scan_add(int* __restrict__ row_ptr,
                                                const int* __restrict__ partials, int N) {
    const int i = blockIdx.x * 256 + threadIdx.x;
    if (i == 0) row_ptr[0] = 0;
    if (i < N) row_ptr[i + 1] += partials[i >> 10];
}

__global__ void scatter_edges(const int* __restrict__ src_in, const int* __restrict__ dst,
                              int E, int ET, const int* __restrict__ row_ptr,
                              int* __restrict__ cursor, int* __restrict__ esrc) {
    const int e = blockIdx.x * blockDim.x + threadIdx.x;
    if (e >= ET) return;
    const int d = (e < E) ? dst[e] : (e - E);
    const int s = (e < E) ? src_in[e] : (e - E);
    const int pos = atomicAdd(&cursor[d], 1);
    esrc[row_ptr[d] + pos] = s;
}

// ---------------------------------------------------------------------------
// GAT aggregation, one WAVE per dst node. Gather reads bf16 h rows (512B/row).
// ---------------------------------------------------------------------------
__global__ __launch_bounds__(256) void gat_aggregate_wave(
    const u16* __restrict__ h_bf, const float* __restrict__ a_src,
    const float* __restrict__ a_dst, const int* __restrict__ row_ptr,
    const int* __restrict__ esrc, const float* __restrict__ bias,
    float* __restrict__ out, int N) {
    __shared__ int   s_src[4][CHW];
    __shared__ float s_ev[4][CHW][NH];

    const int tid = threadIdx.x;
    const int wv = tid >> 6;
    const int lane = tid & 63;
    const int n = blockIdx.x * 4 + wv;
    if (n >= N) return;

    const int beg = row_ptr[n];
    const int deg = row_ptr[n + 1] - beg;
    const int jj = lane >> 3;   // edge slot 0..7
    const int hh = lane & 7;    // head for softmax lanes
    const int g4 = lane >> 3;   // head for gather features

    const float adh = a_dst[n * NH + hh];
    float m_run = -1e30f, d_run = 0.f;
    f32x4 acc = (f32x4)0.f;

    for (int c0 = 0; c0 < deg; c0 += CHW) {
        const int chlen = min(CHW, deg - c0);

        float lmax = -1e30f;
        for (int p = 0; p < chlen; p += 8) {
            const int j = p + jj;
            if (j < chlen) {
                const int s = esrc[beg + c0 + j];
                if (hh == 0) s_src[wv][j] = s;
                float v = a_src[s * NH + hh] + adh;
                v = (v > 0.f) ? v : NEG_SLOPE * v;
                s_ev[wv][j][hh] = v;
                lmax = fmaxf(lmax, v);
            }
        }
        lmax = fmaxf(lmax, __shfl_xor(lmax, 8));
        lmax = fmaxf(lmax, __shfl_xor(lmax, 16));
        lmax = fmaxf(lmax, __shfl_xor(lmax, 32));
        const float mo = m_run;
        const float mn = fmaxf(mo, lmax);
        const float scl = __expf(mo - mn);
        m_run = mn;

        float lsum = 0.f;
        for (int p = 0; p < chlen; p += 8) {
            const int j = p + jj;
            if (j < chlen) {
                const float pv = __expf(s_ev[wv][j][hh] - mn);
                s_ev[wv][j][hh] = pv;
                lsum += pv;
            }
        }
        lsum += __shfl_xor(lsum, 8);
        lsum += __shfl_xor(lsum, 16);
        lsum += __shfl_xor(lsum, 32);
        d_run = d_run * scl + lsum;

        __asm__ volatile("s_waitcnt lgkmcnt(0)" ::: "memory");

        const float scl4 = __shfl(scl, g4);
        f32x4 t0 = (f32x4)0.f, t1 = (f32x4)0.f, t2 = (f32x4)0.f, t3 = (f32x4)0.f;
        int j = 0;
        for (; j + 4 <= chlen; j += 4) {
            const int s0 = s_src[wv][j],     s1 = s_src[wv][j + 1];
            const int s2 = s_src[wv][j + 2], s3 = s_src[wv][j + 3];
            const float p0 = s_ev[wv][j][g4],     p1 = s_ev[wv][j + 1][g4];
            const float p2 = s_ev[wv][j + 2][g4], p3 = s_ev[wv][j + 3][g4];
            const f32x4 h0 = bf4f(*(const ushort4*)&h_bf[(size_t)s0 * HC + lane * 4]);
            const f32x4 h1 = bf4f(*(const ushort4*)&h_bf[(size_t)s1 * HC + lane * 4]);
            const f32x4 h2 = bf4f(*(const ushort4*)&h_bf[(size_t)s2 * HC + lane * 4]);
            const f32x4 h3 = bf4f(*(const ushort4*)&h_bf[(size_t)s3 * HC + lane * 4]);
#pragma unroll
            for (int q = 0; q < 4; q++) {
                t0[q] += p0 * h0[q];
                t1[q] += p1 * h1[q];
                t2[q] += p2 * h2[q];
                t3[q] += p3 * h3[q];
            }
        }
        for (; j < chlen; j++) {
            const int s0 = s_src[wv][j];
            const float p0 = s_ev[wv][j][g4];
            const f32x4 h0 = bf4f(*(const ushort4*)&h_bf[(size_t)s0 * HC + lane * 4]);
#pragma unroll
            for (int q = 0; q < 4; q++) t0[q] += p0 * h0[q];
        }
#pragma unroll
        for (int q = 0; q < 4; q++)
            acc[q] = acc[q] * scl4 + ((t0[q] + t1[q]) + (t2[q] + t3[q]));
    }

    const float invd = 1.f / (__shfl(d_run, g4) + 1e-16f);
    const f32x4 bv = *(const f32x4*)&bias[lane * 4];
    f32x4 o;
#pragma unroll
    for (int q = 0; q < 4; q++) o[q] = fmaxf(acc[q] * invd + bv[q], 0.f);
    *(f32x4*)&out[(size_t)n * HC + lane * 4] = o;
}

// ---------------------------------------------------------------------------
// Pooling stage 1
// ---------------------------------------------------------------------------
__global__ __launch_bounds__(256) void pool_partial(const float* __restrict__ h,
                                                    const int* __restrict__ batch, int N,
                                                    float* __restrict__ sums) {
    __shared__ int bs[64];
    const int tid = threadIdx.x;
    const int base = blockIdx.x * 64;
    const int cnt = min(64, N - base);
    if (tid < 64 && tid < cnt) bs[tid] = batch[base + tid];
    __syncthreads();

    float acc = 0.f;
    int cur = bs[0];
    for (int i = 0; i < cnt; i++) {
        const int g = bs[i];
        if (g != cur) {
            atomicAdd(&sums[(size_t)cur * HC + tid], acc);
            acc = 0.f;
            cur = g;
        }
        acc += h[(size_t)(base + i) * HC + tid];
    }
    atomicAdd(&sums[(size_t)cur * HC + tid], acc);
}

__global__ __launch_bounds__(256) void pool_div(float* __restrict__ sums,
                                                const int* __restrict__ batch, int N) {
    const int g = blockIdx.x;
    const int tid = threadIdx.x;
    int lo = 0, hi = N;
    while (lo < hi) {
        const int mid = (lo + hi) >> 1;
        if (batch[mid] < g) lo = mid + 1; else hi = mid;
    }
    const int start = lo;
    hi = N;
    while (lo < hi) {
        const int mid = (lo + hi) >> 1;
        if (batch[mid] < g + 1) lo = mid + 1; else hi = mid;
    }
    const float inv = 1.f / fmaxf((float)(lo - start), 1.0f);
    sums[(size_t)g * HC + tid] *= inv;
}

// ---------------------------------------------------------------------------
// MLP head
// ---------------------------------------------------------------------------
__global__ __launch_bounds__(128) void mlp_head(const float* __restrict__ pooled,
                                                const float* __restrict__ w1,
                                                const float* __restrict__ b1,
                                                const float* __restrict__ w2,
                                                const float* __restrict__ b2,
                                                float* __restrict__ out) {
    const int g = blockIdx.x;
    const int tid = threadIdx.x;
    __shared__ float p[HC];
    p[tid] = pooled[g * HC + tid];
    p[tid + 128] = pooled[g * HC + tid + 128];
    __syncthreads();
    float z = b1[tid];
#pragma unroll 8
    for (int k = 0; k < HC; k++) z += p[k] * w1[k * 128 + tid];
    z = fmaxf(z, 0.f);
    float t = z * w2[tid];
#pragma unroll
    for (int m = 32; m >= 1; m >>= 1) t += __shfl_xor(t, m);
    __shared__ float ws2[2];
    if ((tid & 63) == 0) ws2[tid >> 6] = t;
    __syncthreads();
    if (tid == 0) out[g] = ws2[0] + ws2[1] + b2[0];
}

// ---------------------------------------------------------------------------
// Host-side launcher
// ---------------------------------------------------------------------------
extern "C" void kernel_launch(void* const* d_in, const int* in_sizes, int n_in,
                              void* d_out, int out_size, void* d_ws, size_t ws_size,
                              hipStream_t stream) {
    const float* x      = (const float*)d_in[0];
    const int*   ei     = (const int*)d_in[1];
    const int*   batch  = (const int*)d_in[2];
    const float* W1     = (const float*)d_in[3];
    const float* as1    = (const float*)d_in[4];
    const float* ad1    = (const float*)d_in[5];
    const float* b1     = (const float*)d_in[6];
    const float* W2     = (const float*)d_in[7];
    const float* as2    = (const float*)d_in[8];
    const float* ad2    = (const float*)d_in[9];
    const float* b2     = (const float*)d_in[10];
    const float* lin1w  = (const float*)d_in[11];
    const float* lin1b  = (const float*)d_in[12];
    const float* lin2w  = (const float*)d_in[13];
    const float* lin2b  = (const float*)d_in[14];

    const int N   = in_sizes[2];       // 50000
    const int E   = in_sizes[1] / 2;   // 800000
    const int ET  = E + N;
    const int Fin = in_sizes[0] / N;   // 1280
    const int NG  = 64;

    const int nRB = (N + 63) / 64;
    const int nScanBlk = (N + 1023) / 1024;

    const int* src_arr = ei;
    const int* dst_arr = ei + E;

    char* ws = (char*)d_ws;
    size_t off = 0;
    auto alloc = [&](size_t bytes) {
        void* p = ws + off;
        off += (bytes + 255) & ~(size_t)255;
        return p;
    };
    float* h_gemm  = (float*)alloc((size_t)N * HC * sizeof(float));
    float* h_agg   = (float*)alloc((size_t)N * HC * sizeof(float));
    u16*   h_bf    = (u16*)alloc((size_t)N * HC * sizeof(u16));
    float* a_src   = (float*)alloc((size_t)N * NH * sizeof(float));
    float* a_dst   = (float*)alloc((size_t)N * NH * sizeof(float));
    int*   deg     = (int*)alloc((size_t)N * sizeof(int));
    int*   cursor  = (int*)alloc((size_t)N * sizeof(int));
    int*   row_ptr = (int*)alloc((size_t)(N + 1) * sizeof(int));
    int*   partials= (int*)alloc((size_t)1024 * sizeof(int));
    int*   esrc    = (int*)alloc((size_t)ET * sizeof(int));
    float* pooled  = (float*)alloc((size_t)NG * HC * sizeof(float));
    u16* Bh = (u16*)alloc((size_t)Fin * HC * sizeof(u16));
    u16* Bl = (u16*)alloc((size_t)Fin * HC * sizeof(u16));
    (void)ws_size; (void)n_in; (void)out_size;

    // ---- CSR build ----
    hipMemsetAsync(deg, 0, (size_t)N * sizeof(int), stream);
    hipMemsetAsync(cursor, 0, (size_t)N * sizeof(int), stream);
    {
        const int blocks = (ET + 255) / 256;
        count_deg<<<blocks, 256, 0, stream>>>(dst_arr, E, ET, deg);
        scan_block<<<nScanBlk, 256, 0, stream>>>(deg, row_ptr, partials, N);
        scan_partials<<<1, 1024, 0, stream>>>(partials, nScanBlk);
        scan_add<<<(N + 255) / 256, 256, 0, stream>>>(row_ptr, partials, N);
        scatter_edges<<<blocks, 256, 0, stream>>>(src_arr, dst_arr, E, ET, row_ptr,
                                                  cursor, esrc);
    }

    const int aggBlocks = (N + 3) / 4;

    // ---- Layer 1 ----
    pack_b_split<<<(Fin / 32) * 4, 256, 0, stream>>>(W1, Fin, Bh, Bl);
    gemm_fused_split<<<nRB, 256, 0, stream>>>(x, Bh, Bl, h_gemm, N, Fin);
    attn_coef<<<N, 256, 0, stream>>>(h_gemm, as1, ad1, a_src, a_dst, h_bf);
    gat_aggregate_wave<<<aggBlocks, 256, 0, stream>>>(h_bf, a_src, a_dst, row_ptr,
                                                      esrc, b1, h_agg, N);

    // ---- Layer 2 ----
    pack_b_split<<<(HC / 32) * 4, 256, 0, stream>>>(W2, HC, Bh, Bl);
    gemm_fused_split<<<nRB, 256, 0, stream>>>(h_agg, Bh, Bl, h_gemm, N, HC);
    attn_coef<<<N, 256, 0, stream>>>(h_gemm, as2, ad2, a_src, a_dst, h_bf);
    gat_aggregate_wave<<<aggBlocks, 256, 0, stream>>>(h_bf, a_src, a_dst, row_ptr,
                                                      esrc, b2, h_agg, N);

    // ---- Pool + MLP head ----
    hipMemsetAsync(pooled, 0, (size_t)NG * HC * sizeof(float), stream);
    pool_partial<<<(N + 63) / 64, 256, 0, stream>>>(h_agg, batch, N, pooled);
    pool_div<<<NG, 256, 0, stream>>>(pooled, batch, N);
    mlp_head<<<NG, 128, 0, stream>>>(pooled, lin1w, lin1b, lin2w, lin2b, (float*)d_out);
}